// Round 15
// baseline (369.399 us; speedup 1.0000x reference)
//
#include <hip/hip_runtime.h>
#include <hip/hip_bf16.h>

#define DIM 128
typedef unsigned int u32;

// bf16x2 pack/unpack: low ushort = even feature, high = odd feature.
__device__ __forceinline__ u32 pack_bf16x2(float a, float b) {
    u32 ua = __float_as_uint(a), ub = __float_as_uint(b);
    ua = (ua + 0x7FFFu + ((ua >> 16) & 1u)) >> 16;        // RNE
    ub = (ub + 0x7FFFu + ((ub >> 16) & 1u)) >> 16;
    return ua | (ub << 16);
}
__device__ __forceinline__ ushort bf16_of(float a) {
    u32 ua = __float_as_uint(a);
    return (ushort)((ua + 0x7FFFu + ((ua >> 16) & 1u)) >> 16);
}
__device__ __forceinline__ float f_of_bf16(ushort h) {
    return __uint_as_float(((u32)h) << 16);
}
__device__ __forceinline__ float2 unpack_bf16x2(u32 h) {
    return make_float2(__uint_as_float(h << 16), __uint_as_float(h & 0xFFFF0000u));
}

__device__ __forceinline__ void accum8(float* acc, uint4 r, float n) {
    float2 p0 = unpack_bf16x2(r.x), p1 = unpack_bf16x2(r.y);
    float2 p2 = unpack_bf16x2(r.z), p3 = unpack_bf16x2(r.w);
    acc[0] = fmaf(p0.x, n, acc[0]); acc[1] = fmaf(p0.y, n, acc[1]);
    acc[2] = fmaf(p1.x, n, acc[2]); acc[3] = fmaf(p1.y, n, acc[3]);
    acc[4] = fmaf(p2.x, n, acc[4]); acc[5] = fmaf(p2.y, n, acc[5]);
    acc[6] = fmaf(p3.x, n, acc[6]); acc[7] = fmaf(p3.y, n, acc[7]);
}

// ======================= count + rank =======================
// rank[e] = this edge's arrival order within its dst bucket (any permutation
// of 0..deg-1 is fine). Also zeroes `total` for the following alloc pass.
__global__ void count_rank(int* __restrict__ deg, const int* __restrict__ dst,
                           int* __restrict__ rank, int* __restrict__ total, int E)
{
    int e = blockIdx.x * blockDim.x + threadIdx.x;
    if (e == 0) *total = 0;
    if (e < E) rank[e] = atomicAdd(&deg[dst[e]], 1);
}

// ======================= CSR offsets =======================
// Buckets padded to x4; pad slots zeroed here (nrm=0 contributes nothing).
// endp[i] = padded end. NOTE: bucket placement across waves is
// nondeterministic (per-wave atomicAdd base) — per-node end stored explicitly.
// Also zeroes sums/cnt/done for the epilogue.
__global__ __launch_bounds__(256) void alloc_offsets(
    const int* __restrict__ deg, int* __restrict__ start, int* __restrict__ endp,
    float* __restrict__ dinv, int* __restrict__ total,
    uint2* __restrict__ csr, int N,
    float* __restrict__ sums, float* __restrict__ cnt, int G,
    int* __restrict__ done)
{
    int i = blockIdx.x * blockDim.x + threadIdx.x;
    int lane = threadIdx.x & 63;
    if (i < G) { sums[i] = 0.f; cnt[i] = 0.f; }
    if (i == 0) *done = 0;
    int d  = (i < N) ? deg[i] : 0;
    int d4 = (d + 3) & ~3;
    int pre = d4;
    #pragma unroll
    for (int off = 1; off < 64; off <<= 1) {
        int v = __shfl_up(pre, off, 64);
        if (lane >= off) pre += v;
    }
    int waveTot = __shfl(pre, 63, 64);
    int base = 0;
    if (lane == 63) base = atomicAdd(total, waveTot);
    base = __shfl(base, 63, 64);
    if (i < N) {
        int st = base + pre - d4;
        start[i] = st;
        endp[i]  = st + d4;
        dinv[i]  = rsqrtf((float)(d + 1));   // +1 self-loop
        for (int p = d; p < d4; ++p)         // zero the <=3 pad slots
            csr[st + p] = make_uint2(0u, 0u);
    }
}

// ======================= GEMM1 body =======================
// Y[node][f] = sum_k X[node][k] * W[k][f]; X fp32, W fp32, Y bf16.
__device__ __forceinline__ void gemm_body0(
    const float* __restrict__ X, const float* __restrict__ W,
    u32* __restrict__ Y, int N, int block)
{
    __shared__ float As[32][72];
    __shared__ float Bs[32][132];
    const int t = threadIdx.x;
    const int node0 = block * 64;
    const int tx = t & 31;
    const int ty = t >> 5;
    const int f0 = tx * 4;
    const int n0 = ty * 8;

    float acc[8][4];
    #pragma unroll
    for (int i = 0; i < 8; ++i)
        #pragma unroll
        for (int j = 0; j < 4; ++j) acc[i][j] = 0.f;

    const int sr  = t >> 3;
    const int sc4 = (t & 7) * 4;

    for (int k0 = 0; k0 < DIM; k0 += 32) {
        #pragma unroll
        for (int half = 0; half < 2; ++half) {
            int r = sr + half * 32;
            int node = node0 + r;
            float v[4] = {0.f, 0.f, 0.f, 0.f};
            if (node < N)
                *(float4*)v = *(const float4*)&X[(size_t)node * DIM + k0 + sc4];
            #pragma unroll
            for (int i = 0; i < 4; ++i) As[sc4 + i][r] = v[i];
        }
        #pragma unroll
        for (int i = 0; i < 4; ++i) {
            int kk = (t >> 5) + i * 8;
            float4 wv = *(const float4*)&W[(size_t)(k0 + kk) * DIM + f0];
            *(float4*)&Bs[kk][f0] = wv;
        }
        __syncthreads();

        #pragma unroll 4
        for (int kk = 0; kk < 32; ++kk) {
            float4 a0 = *(const float4*)&As[kk][n0];
            float4 a1 = *(const float4*)&As[kk][n0 + 4];
            float4 b  = *(const float4*)&Bs[kk][f0];
            float av[8] = {a0.x,a0.y,a0.z,a0.w,a1.x,a1.y,a1.z,a1.w};
            float bv[4] = {b.x,b.y,b.z,b.w};
            #pragma unroll
            for (int i = 0; i < 8; ++i)
                #pragma unroll
                for (int j = 0; j < 4; ++j)
                    acc[i][j] = fmaf(av[i], bv[j], acc[i][j]);
        }
        __syncthreads();
    }

    #pragma unroll
    for (int i = 0; i < 8; ++i) {
        int node = node0 + n0 + i;
        if (node < N) {
            uint2 o;
            o.x = pack_bf16x2(acc[i][0], acc[i][1]);
            o.y = pack_bf16x2(acc[i][2], acc[i][3]);
            *(uint2*)&Y[(size_t)node * 64 + f0 / 2] = o;
        }
    }
}

// Fused: blocks [0,gblocks) run gemm1; the rest scatter edges into CSR
// using the precomputed rank (no atomics: p = start[dst] + rank[e]).
__global__ __launch_bounds__(256) void scatter_gemm1(
    const float* __restrict__ x, const float* __restrict__ W1,
    u32* __restrict__ Y, int N, int gblocks,
    const int* __restrict__ src, const int* __restrict__ dst,
    const int* __restrict__ rank, const int* __restrict__ start,
    const float* __restrict__ dinv, uint2* __restrict__ csr, int E)
{
    if ((int)blockIdx.x < gblocks) {
        gemm_body0(x, W1, Y, N, blockIdx.x);
    } else {
        int e = ((int)blockIdx.x - gblocks) * 256 + threadIdx.x;
        if (e < E) {
            int s = src[e], d = dst[e];
            int p = start[d] + rank[e];
            csr[p] = make_uint2((u32)s, __float_as_uint(dinv[s] * dinv[d]));
        }
    }
}

// ======================= gather core (4 nodes / wave) =====================
// 16 lanes per node; lane gl holds dwords 4gl..4gl+3 (features 8gl..8gl+7).
// Metadata: interleaved (src,nrm) uint2 records, 2 edges per uint4 load.
// Range [st, en_pad) is a multiple of 4 (pads contribute 0).
__device__ __forceinline__ void gather_core(
    const u32* __restrict__ Hl, const uint2* __restrict__ csr,
    const float* __restrict__ dinv, int node, int st, int en_pad, float* acc)
{
    int j = st;
    for (; j + 8 <= en_pad; j += 8) {
        uint4 m0 = *(const uint4*)&csr[j];
        uint4 m1 = *(const uint4*)&csr[j + 2];
        uint4 m2 = *(const uint4*)&csr[j + 4];
        uint4 m3 = *(const uint4*)&csr[j + 6];
        uint4 r0 = *(const uint4*)&Hl[(size_t)m0.x * 64];
        uint4 r1 = *(const uint4*)&Hl[(size_t)m0.z * 64];
        uint4 r2 = *(const uint4*)&Hl[(size_t)m1.x * 64];
        uint4 r3 = *(const uint4*)&Hl[(size_t)m1.z * 64];
        uint4 r4 = *(const uint4*)&Hl[(size_t)m2.x * 64];
        uint4 r5 = *(const uint4*)&Hl[(size_t)m2.z * 64];
        uint4 r6 = *(const uint4*)&Hl[(size_t)m3.x * 64];
        uint4 r7 = *(const uint4*)&Hl[(size_t)m3.z * 64];
        accum8(acc, r0, __uint_as_float(m0.y));
        accum8(acc, r1, __uint_as_float(m0.w));
        accum8(acc, r2, __uint_as_float(m1.y));
        accum8(acc, r3, __uint_as_float(m1.w));
        accum8(acc, r4, __uint_as_float(m2.y));
        accum8(acc, r5, __uint_as_float(m2.w));
        accum8(acc, r6, __uint_as_float(m3.y));
        accum8(acc, r7, __uint_as_float(m3.w));
    }
    if (j < en_pad) {   // exactly one 4-chunk
        uint4 m0 = *(const uint4*)&csr[j];
        uint4 m1 = *(const uint4*)&csr[j + 2];
        uint4 r0 = *(const uint4*)&Hl[(size_t)m0.x * 64];
        uint4 r1 = *(const uint4*)&Hl[(size_t)m0.z * 64];
        uint4 r2 = *(const uint4*)&Hl[(size_t)m1.x * 64];
        uint4 r3 = *(const uint4*)&Hl[(size_t)m1.z * 64];
        accum8(acc, r0, __uint_as_float(m0.y));
        accum8(acc, r1, __uint_as_float(m0.w));
        accum8(acc, r2, __uint_as_float(m1.y));
        accum8(acc, r3, __uint_as_float(m1.w));
    }
    // self-loop
    float di = dinv[node];
    uint4 rs = *(const uint4*)&Hl[(size_t)node * 64];
    accum8(acc, rs, di * di);
}

// ============== gather1 + GEMM2 fused ==============
__global__ __launch_bounds__(256) void gather_gemm(
    const u32* __restrict__ H, u32* __restrict__ O,
    const uint2* __restrict__ csr, const int* __restrict__ start,
    const int* __restrict__ endp, const float* __restrict__ dinv, int N,
    const float* __restrict__ b1, const float* __restrict__ W2)
{
    __shared__ ushort Ws[DIM][136];     // bf16 W2, padded
    __shared__ float  accs[16][132];    // fp32 agg1 rows, padded

    const int t    = threadIdx.x;
    const int grp  = t >> 4;
    const int gl   = t & 15;
    const int node = blockIdx.x * 16 + grp;
    const bool valid = node < N;

    for (int idx = t; idx < DIM * DIM / 4; idx += 256) {
        float4 wv = *(const float4*)&W2[idx * 4];
        int r = (idx * 4) >> 7, c = (idx * 4) & 127;
        Ws[r][c]     = bf16_of(wv.x);
        Ws[r][c + 1] = bf16_of(wv.y);
        Ws[r][c + 2] = bf16_of(wv.z);
        Ws[r][c + 3] = bf16_of(wv.w);
    }

    float acc[8] = {0.f,0.f,0.f,0.f,0.f,0.f,0.f,0.f};
    if (valid) {
        const u32* Hl = H + gl * 4;
        gather_core(Hl, csr, dinv, node, start[node], endp[node], acc);
    }

    {
        int f0 = gl * 8;
        float4 bA = *(const float4*)&b1[f0];
        float4 bB = *(const float4*)&b1[f0 + 4];
        float bb[8] = {bA.x,bA.y,bA.z,bA.w,bB.x,bB.y,bB.z,bB.w};
        #pragma unroll
        for (int i = 0; i < 8; ++i)
            accs[grp][f0 + i] = fmaxf(acc[i] + bb[i], 0.f);
    }
    __syncthreads();

    {
        const int n  = t >> 4;
        const int fb = (t & 15) * 8;
        float o[8] = {0.f,0.f,0.f,0.f,0.f,0.f,0.f,0.f};
        #pragma unroll 4
        for (int k = 0; k < DIM; ++k) {
            float a = accs[n][k];
            const ushort* wr = &Ws[k][fb];
            ushort4 w0 = *(const ushort4*)wr;
            ushort4 w1 = *(const ushort4*)(wr + 4);
            o[0] = fmaf(a, f_of_bf16(w0.x), o[0]);
            o[1] = fmaf(a, f_of_bf16(w0.y), o[1]);
            o[2] = fmaf(a, f_of_bf16(w0.z), o[2]);
            o[3] = fmaf(a, f_of_bf16(w0.w), o[3]);
            o[4] = fmaf(a, f_of_bf16(w1.x), o[4]);
            o[5] = fmaf(a, f_of_bf16(w1.y), o[5]);
            o[6] = fmaf(a, f_of_bf16(w1.z), o[6]);
            o[7] = fmaf(a, f_of_bf16(w1.w), o[7]);
        }
        int onode = blockIdx.x * 16 + n;
        if (onode < N) {
            uint4 ov;
            ov.x = pack_bf16x2(o[0], o[1]);
            ov.y = pack_bf16x2(o[2], o[3]);
            ov.z = pack_bf16x2(o[4], o[5]);
            ov.w = pack_bf16x2(o[6], o[7]);
            *(uint4*)&O[(size_t)onode * 64 + (t & 15) * 4] = ov;
        }
    }
}

// ============== gather2 + pool + final (last-block) fused ==============
__global__ __launch_bounds__(256) void gather_pool(
    const u32* __restrict__ H,
    const uint2* __restrict__ csr, const int* __restrict__ start,
    const int* __restrict__ endp, const float* __restrict__ dinv, int N,
    const float* __restrict__ b2, const float* __restrict__ wlin,
    const int* __restrict__ batch, float* __restrict__ sums, float* __restrict__ cnt,
    int* __restrict__ done, int nblocks,
    const float* __restrict__ blin, float* __restrict__ out, int G)
{
    const int grp  = threadIdx.x >> 4;
    const int gl   = threadIdx.x & 15;
    const int node = blockIdx.x * 16 + grp;

    if (node < N) {
        float acc[8] = {0.f,0.f,0.f,0.f,0.f,0.f,0.f,0.f};
        const u32* Hl = H + gl * 4;
        gather_core(Hl, csr, dinv, node, start[node], endp[node], acc);

        int f0 = gl * 8;
        float v = 0.f;
        #pragma unroll
        for (int i = 0; i < 8; ++i)
            v += fmaxf(acc[i] + b2[f0 + i], 0.f) * wlin[f0 + i];
        #pragma unroll
        for (int m = 1; m <= 8; m <<= 1) v += __shfl_xor(v, m, 64);
        if (gl == 0) {
            int g = batch[node];
            unsafeAtomicAdd(&sums[g], v);
            unsafeAtomicAdd(&cnt[g], 1.0f);
        }
    }

    // last block computes the final output (memory-side atomic reads: safe
    // across per-XCD L2s).
    __syncthreads();                     // drains each wave's pending atomics
    __shared__ int lastflag;
    if (threadIdx.x == 0) {
        __threadfence();
        lastflag = (atomicAdd(done, 1) == nblocks - 1);
    }
    __syncthreads();
    if (lastflag) {
        float b = blin[0];
        for (int g = threadIdx.x; g < G; g += 256) {
            float s = unsafeAtomicAdd(&sums[g], 0.0f);
            float c = unsafeAtomicAdd(&cnt[g], 0.0f);
            out[g] = s / fmaxf(c, 1.0f) + b;
        }
    }
}

// ======================= launch =======================

extern "C" void kernel_launch(void* const* d_in, const int* in_sizes, int n_in,
                              void* d_out, int out_size, void* d_ws, size_t ws_size,
                              hipStream_t stream)
{
    const float* x    = (const float*)d_in[0];
    const int*   src  = (const int*)d_in[1];
    const int*   dst  = (const int*)d_in[2];
    const int*   batch= (const int*)d_in[3];
    const float* W1   = (const float*)d_in[5];
    const float* b1   = (const float*)d_in[6];
    const float* W2   = (const float*)d_in[7];
    const float* b2   = (const float*)d_in[8];
    const float* wlin = (const float*)d_in[9];
    const float* blin = (const float*)d_in[10];
    float* out = (float*)d_out;

    const int N = in_sizes[0] / DIM;
    const int E = in_sizes[1];
    const int G = out_size;
    const size_t E_pad = (size_t)E + 4 * (size_t)N;   // per-bucket pad to x4

    // layout: B0(bf16 N*64 u32), B1, dinv(N), sums(G), cnt(G),
    //         deg(N), start(N), endp(N), rank(E), csr(uint2 E_pad), total, done
    u32*   B0    = (u32*)d_ws;
    u32*   B1    = B0 + (size_t)N * 64;
    float* dinv  = (float*)(B1 + (size_t)N * 64);
    float* sums  = dinv + N;
    float* cnt   = sums + G;
    int*   deg_c = (int*)(cnt + G);
    int*   start = deg_c + N;
    int*   endp  = start + N;
    int*   rank  = endp + N;
    uint2* csr   = (uint2*)(rank + E);
    int*   total = (int*)(csr + E_pad);
    int*   done  = total + 1;
    size_t need_bytes = ((size_t)(done + 1) - (size_t)d_ws);
    if (ws_size < need_bytes) return;

    const int gblocks = (N + 63) / 64;
    const int eblocks = (E + 255) / 256;
    const int g4blocks = (N + 15) / 16;

    hipMemsetAsync(deg_c, 0, sizeof(int) * (size_t)N, stream);
    count_rank<<<eblocks, 256, 0, stream>>>(deg_c, dst, rank, total, E);
    alloc_offsets<<<(N + 255) / 256, 256, 0, stream>>>(deg_c, start, endp,
                                                       dinv, total, csr, N,
                                                       sums, cnt, G, done);
    // gemm1 fused with atomic-free edge scatter
    scatter_gemm1<<<gblocks + eblocks, 256, 0, stream>>>(x, W1, B0, N, gblocks,
                                                         src, dst, rank, start,
                                                         dinv, csr, E);
    // layer 1 aggregation + layer 2 GEMM (fused)
    gather_gemm<<<g4blocks, 256, 0, stream>>>(B0, B1, csr, start, endp, dinv,
                                              N, b1, W2);
    // layer 2 aggregation + pooling + final (fused)
    gather_pool<<<g4blocks, 256, 0, stream>>>(B1, csr, start, endp, dinv, N,
                                              b2, wlin, batch, sums, cnt,
                                              done, g4blocks, blin, out, G);
}

// Round 16
// 304.043 us; speedup vs baseline: 1.2150x; 1.2150x over previous
//
#include <hip/hip_runtime.h>
#include <hip/hip_bf16.h>

#define DIM 128
typedef unsigned int u32;

// bf16x2 pack/unpack: low ushort = even feature, high = odd feature.
__device__ __forceinline__ u32 pack_bf16x2(float a, float b) {
    u32 ua = __float_as_uint(a), ub = __float_as_uint(b);
    ua = (ua + 0x7FFFu + ((ua >> 16) & 1u)) >> 16;        // RNE
    ub = (ub + 0x7FFFu + ((ub >> 16) & 1u)) >> 16;
    return ua | (ub << 16);
}
__device__ __forceinline__ ushort bf16_of(float a) {
    u32 ua = __float_as_uint(a);
    return (ushort)((ua + 0x7FFFu + ((ua >> 16) & 1u)) >> 16);
}
__device__ __forceinline__ float f_of_bf16(ushort h) {
    return __uint_as_float(((u32)h) << 16);
}
__device__ __forceinline__ float2 unpack_bf16x2(u32 h) {
    return make_float2(__uint_as_float(h << 16), __uint_as_float(h & 0xFFFF0000u));
}

__device__ __forceinline__ void accum8(float* acc, uint4 r, float n) {
    float2 p0 = unpack_bf16x2(r.x), p1 = unpack_bf16x2(r.y);
    float2 p2 = unpack_bf16x2(r.z), p3 = unpack_bf16x2(r.w);
    acc[0] = fmaf(p0.x, n, acc[0]); acc[1] = fmaf(p0.y, n, acc[1]);
    acc[2] = fmaf(p1.x, n, acc[2]); acc[3] = fmaf(p1.y, n, acc[3]);
    acc[4] = fmaf(p2.x, n, acc[4]); acc[5] = fmaf(p2.y, n, acc[5]);
    acc[6] = fmaf(p3.x, n, acc[6]); acc[7] = fmaf(p3.y, n, acc[7]);
}

// ======================= count + rank =======================
// rank[e] = edge's arrival order within its dst bucket. Zeroes `total` too.
__global__ void count_rank(int* __restrict__ deg, const int* __restrict__ dst,
                           int* __restrict__ rank, int* __restrict__ total, int E)
{
    int e = blockIdx.x * blockDim.x + threadIdx.x;
    if (e == 0) *total = 0;
    if (e < E) rank[e] = atomicAdd(&deg[dst[e]], 1);
}

// ======================= CSR offsets =======================
// Buckets padded to x4; pad slots zeroed here (nrm=0 contributes nothing).
// endp[i] = padded end. Bucket placement across waves is nondeterministic
// (per-wave atomicAdd base) — per-node end stored explicitly.
__global__ __launch_bounds__(256) void alloc_offsets(
    const int* __restrict__ deg, int* __restrict__ start, int* __restrict__ endp,
    float* __restrict__ dinv, int* __restrict__ total,
    uint2* __restrict__ csr, int N,
    float* __restrict__ sums, float* __restrict__ cnt, int G)
{
    int i = blockIdx.x * blockDim.x + threadIdx.x;
    int lane = threadIdx.x & 63;
    if (i < G) { sums[i] = 0.f; cnt[i] = 0.f; }
    int d  = (i < N) ? deg[i] : 0;
    int d4 = (d + 3) & ~3;
    int pre = d4;
    #pragma unroll
    for (int off = 1; off < 64; off <<= 1) {
        int v = __shfl_up(pre, off, 64);
        if (lane >= off) pre += v;
    }
    int waveTot = __shfl(pre, 63, 64);
    int base = 0;
    if (lane == 63) base = atomicAdd(total, waveTot);
    base = __shfl(base, 63, 64);
    if (i < N) {
        int st = base + pre - d4;
        start[i] = st;
        endp[i]  = st + d4;
        dinv[i]  = rsqrtf((float)(d + 1));   // +1 self-loop
        for (int p = d; p < d4; ++p)         // zero the <=3 pad slots
            csr[st + p] = make_uint2(0u, 0u);
    }
}

// ======================= GEMM1 body =======================
// Y[node][f] = sum_k X[node][k] * W[k][f]; X fp32, W fp32, Y bf16.
__device__ __forceinline__ void gemm_body0(
    const float* __restrict__ X, const float* __restrict__ W,
    u32* __restrict__ Y, int N, int block)
{
    __shared__ float As[32][72];
    __shared__ float Bs[32][132];
    const int t = threadIdx.x;
    const int node0 = block * 64;
    const int tx = t & 31;
    const int ty = t >> 5;
    const int f0 = tx * 4;
    const int n0 = ty * 8;

    float acc[8][4];
    #pragma unroll
    for (int i = 0; i < 8; ++i)
        #pragma unroll
        for (int j = 0; j < 4; ++j) acc[i][j] = 0.f;

    const int sr  = t >> 3;
    const int sc4 = (t & 7) * 4;

    for (int k0 = 0; k0 < DIM; k0 += 32) {
        #pragma unroll
        for (int half = 0; half < 2; ++half) {
            int r = sr + half * 32;
            int node = node0 + r;
            float v[4] = {0.f, 0.f, 0.f, 0.f};
            if (node < N)
                *(float4*)v = *(const float4*)&X[(size_t)node * DIM + k0 + sc4];
            #pragma unroll
            for (int i = 0; i < 4; ++i) As[sc4 + i][r] = v[i];
        }
        #pragma unroll
        for (int i = 0; i < 4; ++i) {
            int kk = (t >> 5) + i * 8;
            float4 wv = *(const float4*)&W[(size_t)(k0 + kk) * DIM + f0];
            *(float4*)&Bs[kk][f0] = wv;
        }
        __syncthreads();

        #pragma unroll 4
        for (int kk = 0; kk < 32; ++kk) {
            float4 a0 = *(const float4*)&As[kk][n0];
            float4 a1 = *(const float4*)&As[kk][n0 + 4];
            float4 b  = *(const float4*)&Bs[kk][f0];
            float av[8] = {a0.x,a0.y,a0.z,a0.w,a1.x,a1.y,a1.z,a1.w};
            float bv[4] = {b.x,b.y,b.z,b.w};
            #pragma unroll
            for (int i = 0; i < 8; ++i)
                #pragma unroll
                for (int j = 0; j < 4; ++j)
                    acc[i][j] = fmaf(av[i], bv[j], acc[i][j]);
        }
        __syncthreads();
    }

    #pragma unroll
    for (int i = 0; i < 8; ++i) {
        int node = node0 + n0 + i;
        if (node < N) {
            uint2 o;
            o.x = pack_bf16x2(acc[i][0], acc[i][1]);
            o.y = pack_bf16x2(acc[i][2], acc[i][3]);
            *(uint2*)&Y[(size_t)node * 64 + f0 / 2] = o;
        }
    }
}

// Fused: blocks [0,gblocks) run gemm1; the rest scatter edges into CSR
// using the precomputed rank (no atomics: p = start[dst] + rank[e]).
__global__ __launch_bounds__(256) void scatter_gemm1(
    const float* __restrict__ x, const float* __restrict__ W1,
    u32* __restrict__ Y, int N, int gblocks,
    const int* __restrict__ src, const int* __restrict__ dst,
    const int* __restrict__ rank, const int* __restrict__ start,
    const float* __restrict__ dinv, uint2* __restrict__ csr, int E)
{
    if ((int)blockIdx.x < gblocks) {
        gemm_body0(x, W1, Y, N, blockIdx.x);
    } else {
        int e = ((int)blockIdx.x - gblocks) * 256 + threadIdx.x;
        if (e < E) {
            int s = src[e], d = dst[e];
            int p = start[d] + rank[e];
            csr[p] = make_uint2((u32)s, __float_as_uint(dinv[s] * dinv[d]));
        }
    }
}

// ======================= gather core (4 nodes / wave) =====================
// 16 lanes per node; lane gl holds dwords 4gl..4gl+3 (features 8gl..8gl+7).
// Metadata: interleaved (src,nrm) uint2 records, 2 edges per uint4 load.
// Range [st, en_pad) is a multiple of 4 (pads contribute 0).
__device__ __forceinline__ void gather_core(
    const u32* __restrict__ Hl, const uint2* __restrict__ csr,
    const float* __restrict__ dinv, int node, int st, int en_pad, float* acc)
{
    int j = st;
    for (; j + 8 <= en_pad; j += 8) {
        uint4 m0 = *(const uint4*)&csr[j];
        uint4 m1 = *(const uint4*)&csr[j + 2];
        uint4 m2 = *(const uint4*)&csr[j + 4];
        uint4 m3 = *(const uint4*)&csr[j + 6];
        uint4 r0 = *(const uint4*)&Hl[(size_t)m0.x * 64];
        uint4 r1 = *(const uint4*)&Hl[(size_t)m0.z * 64];
        uint4 r2 = *(const uint4*)&Hl[(size_t)m1.x * 64];
        uint4 r3 = *(const uint4*)&Hl[(size_t)m1.z * 64];
        uint4 r4 = *(const uint4*)&Hl[(size_t)m2.x * 64];
        uint4 r5 = *(const uint4*)&Hl[(size_t)m2.z * 64];
        uint4 r6 = *(const uint4*)&Hl[(size_t)m3.x * 64];
        uint4 r7 = *(const uint4*)&Hl[(size_t)m3.z * 64];
        accum8(acc, r0, __uint_as_float(m0.y));
        accum8(acc, r1, __uint_as_float(m0.w));
        accum8(acc, r2, __uint_as_float(m1.y));
        accum8(acc, r3, __uint_as_float(m1.w));
        accum8(acc, r4, __uint_as_float(m2.y));
        accum8(acc, r5, __uint_as_float(m2.w));
        accum8(acc, r6, __uint_as_float(m3.y));
        accum8(acc, r7, __uint_as_float(m3.w));
    }
    if (j < en_pad) {   // exactly one 4-chunk
        uint4 m0 = *(const uint4*)&csr[j];
        uint4 m1 = *(const uint4*)&csr[j + 2];
        uint4 r0 = *(const uint4*)&Hl[(size_t)m0.x * 64];
        uint4 r1 = *(const uint4*)&Hl[(size_t)m0.z * 64];
        uint4 r2 = *(const uint4*)&Hl[(size_t)m1.x * 64];
        uint4 r3 = *(const uint4*)&Hl[(size_t)m1.z * 64];
        accum8(acc, r0, __uint_as_float(m0.y));
        accum8(acc, r1, __uint_as_float(m0.w));
        accum8(acc, r2, __uint_as_float(m1.y));
        accum8(acc, r3, __uint_as_float(m1.w));
    }
    // self-loop
    float di = dinv[node];
    uint4 rs = *(const uint4*)&Hl[(size_t)node * 64];
    accum8(acc, rs, di * di);
}

// ============== gather1 + GEMM2 fused ==============
__global__ __launch_bounds__(256) void gather_gemm(
    const u32* __restrict__ H, u32* __restrict__ O,
    const uint2* __restrict__ csr, const int* __restrict__ start,
    const int* __restrict__ endp, const float* __restrict__ dinv, int N,
    const float* __restrict__ b1, const float* __restrict__ W2)
{
    __shared__ ushort Ws[DIM][136];     // bf16 W2, padded
    __shared__ float  accs[16][132];    // fp32 agg1 rows, padded

    const int t    = threadIdx.x;
    const int grp  = t >> 4;
    const int gl   = t & 15;
    const int node = blockIdx.x * 16 + grp;
    const bool valid = node < N;

    for (int idx = t; idx < DIM * DIM / 4; idx += 256) {
        float4 wv = *(const float4*)&W2[idx * 4];
        int r = (idx * 4) >> 7, c = (idx * 4) & 127;
        Ws[r][c]     = bf16_of(wv.x);
        Ws[r][c + 1] = bf16_of(wv.y);
        Ws[r][c + 2] = bf16_of(wv.z);
        Ws[r][c + 3] = bf16_of(wv.w);
    }

    float acc[8] = {0.f,0.f,0.f,0.f,0.f,0.f,0.f,0.f};
    if (valid) {
        const u32* Hl = H + gl * 4;
        gather_core(Hl, csr, dinv, node, start[node], endp[node], acc);
    }

    {
        int f0 = gl * 8;
        float4 bA = *(const float4*)&b1[f0];
        float4 bB = *(const float4*)&b1[f0 + 4];
        float bb[8] = {bA.x,bA.y,bA.z,bA.w,bB.x,bB.y,bB.z,bB.w};
        #pragma unroll
        for (int i = 0; i < 8; ++i)
            accs[grp][f0 + i] = fmaxf(acc[i] + bb[i], 0.f);
    }
    __syncthreads();

    {
        const int n  = t >> 4;
        const int fb = (t & 15) * 8;
        float o[8] = {0.f,0.f,0.f,0.f,0.f,0.f,0.f,0.f};
        #pragma unroll 4
        for (int k = 0; k < DIM; ++k) {
            float a = accs[n][k];
            const ushort* wr = &Ws[k][fb];
            ushort4 w0 = *(const ushort4*)wr;
            ushort4 w1 = *(const ushort4*)(wr + 4);
            o[0] = fmaf(a, f_of_bf16(w0.x), o[0]);
            o[1] = fmaf(a, f_of_bf16(w0.y), o[1]);
            o[2] = fmaf(a, f_of_bf16(w0.z), o[2]);
            o[3] = fmaf(a, f_of_bf16(w0.w), o[3]);
            o[4] = fmaf(a, f_of_bf16(w1.x), o[4]);
            o[5] = fmaf(a, f_of_bf16(w1.y), o[5]);
            o[6] = fmaf(a, f_of_bf16(w1.z), o[6]);
            o[7] = fmaf(a, f_of_bf16(w1.w), o[7]);
        }
        int onode = blockIdx.x * 16 + n;
        if (onode < N) {
            uint4 ov;
            ov.x = pack_bf16x2(o[0], o[1]);
            ov.y = pack_bf16x2(o[2], o[3]);
            ov.z = pack_bf16x2(o[4], o[5]);
            ov.w = pack_bf16x2(o[6], o[7]);
            *(uint4*)&O[(size_t)onode * 64 + (t & 15) * 4] = ov;
        }
    }
}

// ============== gather2 + pool fused (r14 shape: early return, no barrier —
// keeps 44 VGPRs / 8 row-loads in flight; r15's tail fusion dropped VGPRs to
// 36 and serialized the loads, 2x regression) ==============
__global__ __launch_bounds__(256) void gather_pool(
    const u32* __restrict__ H,
    const uint2* __restrict__ csr, const int* __restrict__ start,
    const int* __restrict__ endp, const float* __restrict__ dinv, int N,
    const float* __restrict__ b2, const float* __restrict__ wlin,
    const int* __restrict__ batch, float* __restrict__ sums, float* __restrict__ cnt)
{
    const int grp  = threadIdx.x >> 4;
    const int gl   = threadIdx.x & 15;
    const int node = blockIdx.x * 16 + grp;
    if (node >= N) return;

    float acc[8] = {0.f,0.f,0.f,0.f,0.f,0.f,0.f,0.f};
    const u32* Hl = H + gl * 4;
    gather_core(Hl, csr, dinv, node, start[node], endp[node], acc);

    int f0 = gl * 8;
    float v = 0.f;
    #pragma unroll
    for (int i = 0; i < 8; ++i)
        v += fmaxf(acc[i] + b2[f0 + i], 0.f) * wlin[f0 + i];
    #pragma unroll
    for (int m = 1; m <= 8; m <<= 1) v += __shfl_xor(v, m, 64);
    if (gl == 0) {
        int g = batch[node];
        unsafeAtomicAdd(&sums[g], v);
        unsafeAtomicAdd(&cnt[g], 1.0f);
    }
}

__global__ void final_kernel(const float* __restrict__ sums,
                             const float* __restrict__ cnt,
                             const float* __restrict__ blin,
                             float* __restrict__ out, int G)
{
    int g = blockIdx.x * blockDim.x + threadIdx.x;
    if (g < G) out[g] = sums[g] / fmaxf(cnt[g], 1.0f) + blin[0];
}

// ======================= launch =======================

extern "C" void kernel_launch(void* const* d_in, const int* in_sizes, int n_in,
                              void* d_out, int out_size, void* d_ws, size_t ws_size,
                              hipStream_t stream)
{
    const float* x    = (const float*)d_in[0];
    const int*   src  = (const int*)d_in[1];
    const int*   dst  = (const int*)d_in[2];
    const int*   batch= (const int*)d_in[3];
    const float* W1   = (const float*)d_in[5];
    const float* b1   = (const float*)d_in[6];
    const float* W2   = (const float*)d_in[7];
    const float* b2   = (const float*)d_in[8];
    const float* wlin = (const float*)d_in[9];
    const float* blin = (const float*)d_in[10];
    float* out = (float*)d_out;

    const int N = in_sizes[0] / DIM;
    const int E = in_sizes[1];
    const int G = out_size;
    const size_t E_pad = (size_t)E + 4 * (size_t)N;   // per-bucket pad to x4

    // layout: B0(bf16 N*64 u32), B1, dinv(N), sums(G), cnt(G),
    //         deg(N), start(N), endp(N), rank(E), csr(uint2 E_pad), total
    u32*   B0    = (u32*)d_ws;
    u32*   B1    = B0 + (size_t)N * 64;
    float* dinv  = (float*)(B1 + (size_t)N * 64);
    float* sums  = dinv + N;
    float* cnt   = sums + G;
    int*   deg_c = (int*)(cnt + G);
    int*   start = deg_c + N;
    int*   endp  = start + N;
    int*   rank  = endp + N;
    uint2* csr   = (uint2*)(rank + E);
    int*   total = (int*)(csr + E_pad);
    size_t need_bytes = ((size_t)(total + 1) - (size_t)d_ws);
    if (ws_size < need_bytes) return;

    const int gblocks = (N + 63) / 64;
    const int eblocks = (E + 255) / 256;
    const int g4blocks = (N + 15) / 16;

    hipMemsetAsync(deg_c, 0, sizeof(int) * (size_t)N, stream);
    count_rank<<<eblocks, 256, 0, stream>>>(deg_c, dst, rank, total, E);
    alloc_offsets<<<(N + 255) / 256, 256, 0, stream>>>(deg_c, start, endp,
                                                       dinv, total, csr, N,
                                                       sums, cnt, G);
    // gemm1 fused with atomic-free edge scatter
    scatter_gemm1<<<gblocks + eblocks, 256, 0, stream>>>(x, W1, B0, N, gblocks,
                                                         src, dst, rank, start,
                                                         dinv, csr, E);
    // layer 1 aggregation + layer 2 GEMM (fused)
    gather_gemm<<<g4blocks, 256, 0, stream>>>(B0, B1, csr, start, endp, dinv,
                                              N, b1, W2);
    // layer 2 aggregation + pooling (fused)
    gather_pool<<<g4blocks, 256, 0, stream>>>(B1, csr, start, endp, dinv, N,
                                              b2, wlin, batch, sums, cnt);
    final_kernel<<<(G + 255) / 256, 256, 0, stream>>>(sums, cnt, blin, out, G);
}

// Round 17
// 302.637 us; speedup vs baseline: 1.2206x; 1.0046x over previous
//
#include <hip/hip_runtime.h>
#include <hip/hip_bf16.h>

#define DIM 128
typedef unsigned int u32;

// bf16x2 pack/unpack: low ushort = even feature, high = odd feature.
__device__ __forceinline__ u32 pack_bf16x2(float a, float b) {
    u32 ua = __float_as_uint(a), ub = __float_as_uint(b);
    ua = (ua + 0x7FFFu + ((ua >> 16) & 1u)) >> 16;        // RNE
    ub = (ub + 0x7FFFu + ((ub >> 16) & 1u)) >> 16;
    return ua | (ub << 16);
}
__device__ __forceinline__ ushort bf16_of(float a) {
    u32 ua = __float_as_uint(a);
    return (ushort)((ua + 0x7FFFu + ((ua >> 16) & 1u)) >> 16);
}
__device__ __forceinline__ float f_of_bf16(ushort h) {
    return __uint_as_float(((u32)h) << 16);
}
__device__ __forceinline__ float2 unpack_bf16x2(u32 h) {
    return make_float2(__uint_as_float(h << 16), __uint_as_float(h & 0xFFFF0000u));
}

__device__ __forceinline__ void add8(float* acc, uint4 r) {
    float2 p0 = unpack_bf16x2(r.x), p1 = unpack_bf16x2(r.y);
    float2 p2 = unpack_bf16x2(r.z), p3 = unpack_bf16x2(r.w);
    acc[0] += p0.x; acc[1] += p0.y;
    acc[2] += p1.x; acc[3] += p1.y;
    acc[4] += p2.x; acc[5] += p2.y;
    acc[6] += p3.x; acc[7] += p3.y;
}

// ======================= count + rank =======================
// rank[e] = edge's arrival order within its dst bucket. Zeroes `total` too.
__global__ void count_rank(int* __restrict__ deg, const int* __restrict__ dst,
                           int* __restrict__ rank, int* __restrict__ total, int E)
{
    int e = blockIdx.x * blockDim.x + threadIdx.x;
    if (e == 0) *total = 0;
    if (e < E) rank[e] = atomicAdd(&deg[dst[e]], 1);
}

// ======================= CSR offsets =======================
// Buckets padded to x4; pad slots point at the zero row (index N).
// endp[i] = padded end. Bucket placement across waves is nondeterministic
// (per-wave atomicAdd base) — per-node end stored explicitly.
// Also zeroes sums/cnt and the zero rows of B0/B1 (row N).
__global__ __launch_bounds__(256) void alloc_offsets(
    const int* __restrict__ deg, int* __restrict__ start, int* __restrict__ endp,
    float* __restrict__ dinv, int* __restrict__ total,
    int* __restrict__ csr, int N,
    float* __restrict__ sums, float* __restrict__ cnt, int G,
    u32* __restrict__ B0, u32* __restrict__ B1)
{
    int i = blockIdx.x * blockDim.x + threadIdx.x;
    int lane = threadIdx.x & 63;
    if (i < G) { sums[i] = 0.f; cnt[i] = 0.f; }
    if (i < 64) {                          // zero row N of both H buffers
        B0[(size_t)N * 64 + i] = 0u;
        B1[(size_t)N * 64 + i] = 0u;
    }
    int d  = (i < N) ? deg[i] : 0;
    int d4 = (d + 3) & ~3;
    int pre = d4;
    #pragma unroll
    for (int off = 1; off < 64; off <<= 1) {
        int v = __shfl_up(pre, off, 64);
        if (lane >= off) pre += v;
    }
    int waveTot = __shfl(pre, 63, 64);
    int base = 0;
    if (lane == 63) base = atomicAdd(total, waveTot);
    base = __shfl(base, 63, 64);
    if (i < N) {
        int st = base + pre - d4;
        start[i] = st;
        endp[i]  = st + d4;
        dinv[i]  = rsqrtf((float)(d + 1));   // +1 self-loop
        for (int p = d; p < d4; ++p)         // pads -> zero row
            csr[st + p] = N;
    }
}

// ======================= GEMM1 body =======================
// Y[node] = bf16(dinv[node] * (X[node] @ W)); X fp32, W fp32.
__device__ __forceinline__ void gemm_body0(
    const float* __restrict__ X, const float* __restrict__ W,
    const float* __restrict__ dinv, u32* __restrict__ Y, int N, int block)
{
    __shared__ float As[32][72];
    __shared__ float Bs[32][132];
    const int t = threadIdx.x;
    const int node0 = block * 64;
    const int tx = t & 31;
    const int ty = t >> 5;
    const int f0 = tx * 4;
    const int n0 = ty * 8;

    float acc[8][4];
    #pragma unroll
    for (int i = 0; i < 8; ++i)
        #pragma unroll
        for (int j = 0; j < 4; ++j) acc[i][j] = 0.f;

    const int sr  = t >> 3;
    const int sc4 = (t & 7) * 4;

    for (int k0 = 0; k0 < DIM; k0 += 32) {
        #pragma unroll
        for (int half = 0; half < 2; ++half) {
            int r = sr + half * 32;
            int node = node0 + r;
            float v[4] = {0.f, 0.f, 0.f, 0.f};
            if (node < N)
                *(float4*)v = *(const float4*)&X[(size_t)node * DIM + k0 + sc4];
            #pragma unroll
            for (int i = 0; i < 4; ++i) As[sc4 + i][r] = v[i];
        }
        #pragma unroll
        for (int i = 0; i < 4; ++i) {
            int kk = (t >> 5) + i * 8;
            float4 wv = *(const float4*)&W[(size_t)(k0 + kk) * DIM + f0];
            *(float4*)&Bs[kk][f0] = wv;
        }
        __syncthreads();

        #pragma unroll 4
        for (int kk = 0; kk < 32; ++kk) {
            float4 a0 = *(const float4*)&As[kk][n0];
            float4 a1 = *(const float4*)&As[kk][n0 + 4];
            float4 b  = *(const float4*)&Bs[kk][f0];
            float av[8] = {a0.x,a0.y,a0.z,a0.w,a1.x,a1.y,a1.z,a1.w};
            float bv[4] = {b.x,b.y,b.z,b.w};
            #pragma unroll
            for (int i = 0; i < 8; ++i)
                #pragma unroll
                for (int j = 0; j < 4; ++j)
                    acc[i][j] = fmaf(av[i], bv[j], acc[i][j]);
        }
        __syncthreads();
    }

    #pragma unroll
    for (int i = 0; i < 8; ++i) {
        int node = node0 + n0 + i;
        if (node < N) {
            float dn = dinv[node];
            uint2 o;
            o.x = pack_bf16x2(dn * acc[i][0], dn * acc[i][1]);
            o.y = pack_bf16x2(dn * acc[i][2], dn * acc[i][3]);
            *(uint2*)&Y[(size_t)node * 64 + f0 / 2] = o;
        }
    }
}

// Fused: blocks [0,gblocks) run gemm1; the rest scatter edge src into CSR
// using the precomputed rank (no atomics: p = start[dst] + rank[e]).
__global__ __launch_bounds__(256) void scatter_gemm1(
    const float* __restrict__ x, const float* __restrict__ W1,
    const float* __restrict__ dinv, u32* __restrict__ Y, int N, int gblocks,
    const int* __restrict__ src, const int* __restrict__ dst,
    const int* __restrict__ rank, const int* __restrict__ start,
    int* __restrict__ csr, int E)
{
    if ((int)blockIdx.x < gblocks) {
        gemm_body0(x, W1, dinv, Y, N, blockIdx.x);
    } else {
        int e = ((int)blockIdx.x - gblocks) * 256 + threadIdx.x;
        if (e < E) {
            int d = dst[e];
            csr[start[d] + rank[e]] = src[e];
        }
    }
}

// ======================= gather core (4 nodes / wave) =====================
// 16 lanes per node; lane gl holds dwords 4gl..4gl+3 (features 8gl..8gl+7).
// Rows are pre-scaled by dinv[src] (stored Hd = dinv*h) -> plain adds.
// Metadata: 4 src per int4. Range [st, en_pad) is a multiple of 4; pad
// entries index the zero row N.
__device__ __forceinline__ void gather_core(
    const u32* __restrict__ Hl, const int* __restrict__ csr,
    int st, int en_pad, float* acc)
{
    int j = st;
    for (; j + 8 <= en_pad; j += 8) {
        int4 sa = *(const int4*)&csr[j];
        int4 sb = *(const int4*)&csr[j + 4];
        uint4 r0 = *(const uint4*)&Hl[(size_t)sa.x * 64];
        uint4 r1 = *(const uint4*)&Hl[(size_t)sa.y * 64];
        uint4 r2 = *(const uint4*)&Hl[(size_t)sa.z * 64];
        uint4 r3 = *(const uint4*)&Hl[(size_t)sa.w * 64];
        uint4 r4 = *(const uint4*)&Hl[(size_t)sb.x * 64];
        uint4 r5 = *(const uint4*)&Hl[(size_t)sb.y * 64];
        uint4 r6 = *(const uint4*)&Hl[(size_t)sb.z * 64];
        uint4 r7 = *(const uint4*)&Hl[(size_t)sb.w * 64];
        add8(acc, r0); add8(acc, r1); add8(acc, r2); add8(acc, r3);
        add8(acc, r4); add8(acc, r5); add8(acc, r6); add8(acc, r7);
    }
    if (j < en_pad) {   // exactly one 4-chunk
        int4 sa = *(const int4*)&csr[j];
        uint4 r0 = *(const uint4*)&Hl[(size_t)sa.x * 64];
        uint4 r1 = *(const uint4*)&Hl[(size_t)sa.y * 64];
        uint4 r2 = *(const uint4*)&Hl[(size_t)sa.z * 64];
        uint4 r3 = *(const uint4*)&Hl[(size_t)sa.w * 64];
        add8(acc, r0); add8(acc, r1); add8(acc, r2); add8(acc, r3);
    }
}

// ============== gather1 + GEMM2 fused ==============
// agg1[d] = dinv[d]*(sum Hd[s] + Hd[d]); h2 = relu(agg1+b1) @ W2;
// writes B1 pre-scaled: bf16(dinv*h2).
__global__ __launch_bounds__(256) void gather_gemm(
    const u32* __restrict__ H, u32* __restrict__ O,
    const int* __restrict__ csr, const int* __restrict__ start,
    const int* __restrict__ endp, const float* __restrict__ dinv, int N,
    const float* __restrict__ b1, const float* __restrict__ W2)
{
    __shared__ ushort Ws[DIM][136];     // bf16 W2, padded
    __shared__ float  accs[16][132];    // fp32 agg1 rows, padded

    const int t    = threadIdx.x;
    const int grp  = t >> 4;
    const int gl   = t & 15;
    const int node = blockIdx.x * 16 + grp;
    const bool valid = node < N;

    for (int idx = t; idx < DIM * DIM / 4; idx += 256) {
        float4 wv = *(const float4*)&W2[idx * 4];
        int r = (idx * 4) >> 7, c = (idx * 4) & 127;
        Ws[r][c]     = bf16_of(wv.x);
        Ws[r][c + 1] = bf16_of(wv.y);
        Ws[r][c + 2] = bf16_of(wv.z);
        Ws[r][c + 3] = bf16_of(wv.w);
    }

    float acc[8] = {0.f,0.f,0.f,0.f,0.f,0.f,0.f,0.f};
    float dn = 0.f;
    if (valid) {
        const u32* Hl = H + gl * 4;
        gather_core(Hl, csr, start[node], endp[node], acc);
        add8(acc, *(const uint4*)&Hl[(size_t)node * 64]);   // self-loop
        dn = dinv[node];
    }

    {
        int f0 = gl * 8;
        float4 bA = *(const float4*)&b1[f0];
        float4 bB = *(const float4*)&b1[f0 + 4];
        float bb[8] = {bA.x,bA.y,bA.z,bA.w,bB.x,bB.y,bB.z,bB.w};
        #pragma unroll
        for (int i = 0; i < 8; ++i)
            accs[grp][f0 + i] = fmaxf(fmaf(dn, acc[i], bb[i]), 0.f);
    }
    __syncthreads();

    {
        const int n  = t >> 4;
        const int fb = (t & 15) * 8;
        float o[8] = {0.f,0.f,0.f,0.f,0.f,0.f,0.f,0.f};
        #pragma unroll 4
        for (int k = 0; k < DIM; ++k) {
            float a = accs[n][k];
            const ushort* wr = &Ws[k][fb];
            ushort4 w0 = *(const ushort4*)wr;
            ushort4 w1 = *(const ushort4*)(wr + 4);
            o[0] = fmaf(a, f_of_bf16(w0.x), o[0]);
            o[1] = fmaf(a, f_of_bf16(w0.y), o[1]);
            o[2] = fmaf(a, f_of_bf16(w0.z), o[2]);
            o[3] = fmaf(a, f_of_bf16(w0.w), o[3]);
            o[4] = fmaf(a, f_of_bf16(w1.x), o[4]);
            o[5] = fmaf(a, f_of_bf16(w1.y), o[5]);
            o[6] = fmaf(a, f_of_bf16(w1.z), o[6]);
            o[7] = fmaf(a, f_of_bf16(w1.w), o[7]);
        }
        int onode = blockIdx.x * 16 + n;
        if (onode < N) {
            float dno = dinv[onode];
            uint4 ov;
            ov.x = pack_bf16x2(dno * o[0], dno * o[1]);
            ov.y = pack_bf16x2(dno * o[2], dno * o[3]);
            ov.z = pack_bf16x2(dno * o[4], dno * o[5]);
            ov.w = pack_bf16x2(dno * o[6], dno * o[7]);
            *(uint4*)&O[(size_t)onode * 64 + (t & 15) * 4] = ov;
        }
    }
}

// ============== gather2 + pool fused (early return, no barrier — keeps
// 8 row-loads in flight; see r15 codegen regression note) ==============
__global__ __launch_bounds__(256) void gather_pool(
    const u32* __restrict__ H,
    const int* __restrict__ csr, const int* __restrict__ start,
    const int* __restrict__ endp, const float* __restrict__ dinv, int N,
    const float* __restrict__ b2, const float* __restrict__ wlin,
    const int* __restrict__ batch, float* __restrict__ sums, float* __restrict__ cnt)
{
    const int grp  = threadIdx.x >> 4;
    const int gl   = threadIdx.x & 15;
    const int node = blockIdx.x * 16 + grp;
    if (node >= N) return;

    float acc[8] = {0.f,0.f,0.f,0.f,0.f,0.f,0.f,0.f};
    const u32* Hl = H + gl * 4;
    gather_core(Hl, csr, start[node], endp[node], acc);
    add8(acc, *(const uint4*)&Hl[(size_t)node * 64]);   // self-loop
    float dn = dinv[node];

    int f0 = gl * 8;
    float v = 0.f;
    #pragma unroll
    for (int i = 0; i < 8; ++i)
        v += fmaxf(fmaf(dn, acc[i], b2[f0 + i]), 0.f) * wlin[f0 + i];
    #pragma unroll
    for (int m = 1; m <= 8; m <<= 1) v += __shfl_xor(v, m, 64);
    if (gl == 0) {
        int g = batch[node];
        unsafeAtomicAdd(&sums[g], v);
        unsafeAtomicAdd(&cnt[g], 1.0f);
    }
}

__global__ void final_kernel(const float* __restrict__ sums,
                             const float* __restrict__ cnt,
                             const float* __restrict__ blin,
                             float* __restrict__ out, int G)
{
    int g = blockIdx.x * blockDim.x + threadIdx.x;
    if (g < G) out[g] = sums[g] / fmaxf(cnt[g], 1.0f) + blin[0];
}

// ======================= launch =======================

extern "C" void kernel_launch(void* const* d_in, const int* in_sizes, int n_in,
                              void* d_out, int out_size, void* d_ws, size_t ws_size,
                              hipStream_t stream)
{
    const float* x    = (const float*)d_in[0];
    const int*   src  = (const int*)d_in[1];
    const int*   dst  = (const int*)d_in[2];
    const int*   batch= (const int*)d_in[3];
    const float* W1   = (const float*)d_in[5];
    const float* b1   = (const float*)d_in[6];
    const float* W2   = (const float*)d_in[7];
    const float* b2   = (const float*)d_in[8];
    const float* wlin = (const float*)d_in[9];
    const float* blin = (const float*)d_in[10];
    float* out = (float*)d_out;

    const int N = in_sizes[0] / DIM;
    const int E = in_sizes[1];
    const int G = out_size;
    const size_t E_pad = (size_t)E + 4 * (size_t)N;   // per-bucket pad to x4

    // layout: B0((N+1)*64 u32, row N = zero row), B1 likewise, dinv(N),
    //         sums(G), cnt(G), deg(N), start(N), endp(N), rank(E),
    //         csr(int E_pad), total
    u32*   B0    = (u32*)d_ws;
    u32*   B1    = B0 + (size_t)(N + 1) * 64;
    float* dinv  = (float*)(B1 + (size_t)(N + 1) * 64);
    float* sums  = dinv + N;
    float* cnt   = sums + G;
    int*   deg_c = (int*)(cnt + G);
    int*   start = deg_c + N;
    int*   endp  = start + N;
    int*   rank  = endp + N;
    int*   csr   = rank + E;
    int*   total = csr + E_pad;
    size_t need_bytes = ((size_t)(total + 1) - (size_t)d_ws);
    if (ws_size < need_bytes) return;

    const int gblocks = (N + 63) / 64;
    const int eblocks = (E + 255) / 256;
    const int g4blocks = (N + 15) / 16;

    hipMemsetAsync(deg_c, 0, sizeof(int) * (size_t)N, stream);
    count_rank<<<eblocks, 256, 0, stream>>>(deg_c, dst, rank, total, E);
    alloc_offsets<<<(N + 255) / 256, 256, 0, stream>>>(deg_c, start, endp,
                                                       dinv, total, csr, N,
                                                       sums, cnt, G, B0, B1);
    // gemm1 (pre-scaled output) fused with atomic-free edge scatter
    scatter_gemm1<<<gblocks + eblocks, 256, 0, stream>>>(x, W1, dinv, B0, N,
                                                         gblocks, src, dst,
                                                         rank, start, csr, E);
    // layer 1 aggregation + layer 2 GEMM (fused)
    gather_gemm<<<g4blocks, 256, 0, stream>>>(B0, B1, csr, start, endp, dinv,
                                              N, b1, W2);
    // layer 2 aggregation + pooling (fused)
    gather_pool<<<g4blocks, 256, 0, stream>>>(B1, csr, start, endp, dinv, N,
                                              b2, wlin, batch, sums, cnt);
    final_kernel<<<(G + 255) / 256, 256, 0, stream>>>(sums, cnt, blin, out, G);
}